// Round 1
// baseline (1076.781 us; speedup 1.0000x reference)
//
#include <hip/hip_runtime.h>
#include <hip/hip_bf16.h>

#define T_TOK 8192
#define HDIM 1024
#define FDIM 2048
#define NEXP 8
#define NASSIGN (T_TOK * 2)

typedef __bf16 bf16;
typedef __bf16 bf16x4 __attribute__((ext_vector_type(4)));
typedef __bf16 bf16x8 __attribute__((ext_vector_type(8)));
typedef float f32x4 __attribute__((ext_vector_type(4)));

// ---------------- init: zero expert counters ----------------
__global__ void init_kernel(int* cnt) {
    if (threadIdx.x < NEXP) cnt[threadIdx.x] = 0;
}

// ---------------- transpose + fp32->bf16 convert ----------------
// in: [E][R][C] fp32 ; out: [E][C][R] bf16
__global__ __launch_bounds__(256) void transpose_to_bf16(
    const float* __restrict__ in, bf16* __restrict__ out, int R, int C) {
    __shared__ float tile[32][33];
    int e = blockIdx.z;
    const float* inp = in + (size_t)e * R * C;
    bf16* outp = out + (size_t)e * R * C;
    int c0 = blockIdx.x * 32, r0 = blockIdx.y * 32;
    int tx = threadIdx.x, ty = threadIdx.y;  // (32,8)
#pragma unroll
    for (int i = 0; i < 4; i++)
        tile[ty + 8 * i][tx] = inp[(size_t)(r0 + ty + 8 * i) * C + c0 + tx];
    __syncthreads();
#pragma unroll
    for (int i = 0; i < 4; i++)
        outp[(size_t)(c0 + ty + 8 * i) * R + r0 + tx] = (bf16)tile[tx][ty + 8 * i];
}

// ---------------- router: logits, top-2, softmax, build lists ----------------
__global__ __launch_bounds__(256) void router_kernel(
    const float* __restrict__ x, const float* __restrict__ rw,
    const float* __restrict__ rb, int* __restrict__ cnt, int* __restrict__ perm,
    float* __restrict__ gatebuf, int* __restrict__ slotbuf) {
    int wave = threadIdx.x >> 6;
    int lane = threadIdx.x & 63;
    int t = blockIdx.x * 4 + wave;
    float p[NEXP];
#pragma unroll
    for (int e = 0; e < NEXP; e++) p[e] = 0.f;
    const float* xt = x + (size_t)t * HDIM;
    for (int h = lane; h < HDIM; h += 64) {
        float xv = xt[h];
        const float* r = rw + h * NEXP;
#pragma unroll
        for (int e = 0; e < NEXP; e++) p[e] += xv * r[e];
    }
#pragma unroll
    for (int off = 32; off >= 1; off >>= 1) {
#pragma unroll
        for (int e = 0; e < NEXP; e++) p[e] += __shfl_xor(p[e], off, 64);
    }
    if (lane == 0) {
        float lg[NEXP];
#pragma unroll
        for (int e = 0; e < NEXP; e++) lg[e] = p[e] + rb[e];
        int e0 = 0;
#pragma unroll
        for (int e = 1; e < NEXP; e++)
            if (lg[e] > lg[e0]) e0 = e;
        int e1 = -1;
#pragma unroll
        for (int e = 0; e < NEXP; e++) {
            if (e == e0) continue;
            if (e1 < 0 || lg[e] > lg[e1]) e1 = e;
        }
        float z = expf(lg[e1] - lg[e0]);
        float g0 = 1.f / (1.f + z);
        float g1 = z / (1.f + z);
        int p0 = atomicAdd(&cnt[e0], 1);
        int p1 = atomicAdd(&cnt[e1], 1);
        perm[e0 * T_TOK + p0] = t;
        gatebuf[e0 * T_TOK + p0] = g0;
        slotbuf[2 * t] = e0 * T_TOK + p0;
        perm[e1 * T_TOK + p1] = t;
        gatebuf[e1 * T_TOK + p1] = g1;
        slotbuf[2 * t + 1] = e1 * T_TOK + p1;
    }
}

// ---------------- exclusive scan over 8 counts ----------------
__global__ void offsets_kernel(const int* __restrict__ cnt, int* __restrict__ offs) {
    if (threadIdx.x == 0 && blockIdx.x == 0) {
        int o = 0;
        for (int e = 0; e < NEXP; e++) {
            offs[e] = o;
            o += cnt[e];
        }
    }
}

// ---------------- GEMM1: h = relu(x_gather @ w1 + b1), bf16 out ----------------
// A: gathered x rows (fp32 -> bf16), K=HDIM.  B: w1t [F][H] bf16 (k-contig).
__global__ __launch_bounds__(256) void gemm1_kernel(
    const float* __restrict__ x, const bf16* __restrict__ w1t,
    const float* __restrict__ b1, const int* __restrict__ cnt,
    const int* __restrict__ offs, const int* __restrict__ perm,
    bf16* __restrict__ hbuf) {
    int e = blockIdx.z;
    int n_cnt = cnt[e];
    int m0 = blockIdx.x * 128;
    if (m0 >= n_cnt) return;
    int n0 = blockIdx.y * 128;
    __shared__ bf16 As[128][40];
    __shared__ bf16 Bs[128][40];
    int tid = threadIdx.x;
    int lane = tid & 63;
    int wave = tid >> 6;
    int wm = (wave & 1) * 64, wn = (wave >> 1) * 64;
    int quad = lane >> 4;
    int l16 = lane & 15;
    const bf16* bsrc = w1t + (size_t)e * FDIM * HDIM;
    const int* permE = perm + e * T_TOK;
    f32x4 acc[4][4];
#pragma unroll
    for (int i = 0; i < 4; i++)
#pragma unroll
        for (int j = 0; j < 4; j++) acc[i][j] = f32x4{0.f, 0.f, 0.f, 0.f};

    for (int k0 = 0; k0 < HDIM; k0 += 32) {
        // stage A: 128 rows x 32 k (gather + fp32->bf16)
#pragma unroll
        for (int it = 0; it < 4; it++) {
            int idx = tid + it * 256;
            int row = idx >> 3;
            int k4 = idx & 7;
            int gm = m0 + row;
            float4 v = make_float4(0.f, 0.f, 0.f, 0.f);
            if (gm < n_cnt) {
                int tok = permE[gm];
                v = *(const float4*)&x[(size_t)tok * HDIM + k0 + k4 * 4];
            }
            bf16x4 bv = {(bf16)v.x, (bf16)v.y, (bf16)v.z, (bf16)v.w};
            *(bf16x4*)&As[row][k4 * 4] = bv;
        }
        // stage B: 128 n-rows x 32 k, bf16, 16B loads
#pragma unroll
        for (int it = 0; it < 2; it++) {
            int idx = tid + it * 256;
            int row = idx >> 2;
            int q = idx & 3;
            bf16x8 bv = *(const bf16x8*)&bsrc[(size_t)(n0 + row) * HDIM + k0 + q * 8];
            *(bf16x8*)&Bs[row][q * 8] = bv;
        }
        __syncthreads();
        bf16x8 af[4], bfr[4];
#pragma unroll
        for (int i = 0; i < 4; i++)
            af[i] = *(const bf16x8*)&As[wm + i * 16 + l16][quad * 8];
#pragma unroll
        for (int j = 0; j < 4; j++)
            bfr[j] = *(const bf16x8*)&Bs[wn + j * 16 + l16][quad * 8];
#pragma unroll
        for (int i = 0; i < 4; i++)
#pragma unroll
            for (int j = 0; j < 4; j++)
                acc[i][j] = __builtin_amdgcn_mfma_f32_16x16x32_bf16(af[i], bfr[j], acc[i][j], 0, 0, 0);
        __syncthreads();
    }
    int off_e = offs[e];
#pragma unroll
    for (int i = 0; i < 4; i++)
#pragma unroll
        for (int j = 0; j < 4; j++)
#pragma unroll
            for (int r = 0; r < 4; r++) {
                int m = m0 + wm + i * 16 + quad * 4 + r;
                if (m < n_cnt) {
                    int n = n0 + wn + j * 16 + l16;
                    float v = acc[i][j][r] + b1[e * FDIM + n];
                    v = v > 0.f ? v : 0.f;
                    hbuf[(size_t)(off_e + m) * FDIM + n] = (bf16)v;
                }
            }
}

// ---------------- GEMM2: eout = gate * (h @ w2 + b2), bf16 out ----------------
__global__ __launch_bounds__(256) void gemm2_kernel(
    const bf16* __restrict__ hbuf, const bf16* __restrict__ w2t,
    const float* __restrict__ b2, const int* __restrict__ cnt,
    const int* __restrict__ offs, const float* __restrict__ gatebuf,
    bf16* __restrict__ eout) {
    int e = blockIdx.z;
    int n_cnt = cnt[e];
    int m0 = blockIdx.x * 128;
    if (m0 >= n_cnt) return;
    int n0 = blockIdx.y * 128;
    __shared__ bf16 As[128][40];
    __shared__ bf16 Bs[128][40];
    int tid = threadIdx.x;
    int lane = tid & 63;
    int wave = tid >> 6;
    int wm = (wave & 1) * 64, wn = (wave >> 1) * 64;
    int quad = lane >> 4;
    int l16 = lane & 15;
    int off_e = offs[e];
    const bf16* asrc = hbuf + (size_t)off_e * FDIM;
    const bf16* bsrc = w2t + (size_t)e * HDIM * FDIM;
    f32x4 acc[4][4];
#pragma unroll
    for (int i = 0; i < 4; i++)
#pragma unroll
        for (int j = 0; j < 4; j++) acc[i][j] = f32x4{0.f, 0.f, 0.f, 0.f};

    for (int k0 = 0; k0 < FDIM; k0 += 32) {
#pragma unroll
        for (int it = 0; it < 2; it++) {
            int idx = tid + it * 256;
            int row = idx >> 2;
            int q = idx & 3;
            bf16x8 av = *(const bf16x8*)&asrc[(size_t)(m0 + row) * FDIM + k0 + q * 8];
            *(bf16x8*)&As[row][q * 8] = av;
        }
#pragma unroll
        for (int it = 0; it < 2; it++) {
            int idx = tid + it * 256;
            int row = idx >> 2;
            int q = idx & 3;
            bf16x8 bv = *(const bf16x8*)&bsrc[(size_t)(n0 + row) * FDIM + k0 + q * 8];
            *(bf16x8*)&Bs[row][q * 8] = bv;
        }
        __syncthreads();
        bf16x8 af[4], bfr[4];
#pragma unroll
        for (int i = 0; i < 4; i++)
            af[i] = *(const bf16x8*)&As[wm + i * 16 + l16][quad * 8];
#pragma unroll
        for (int j = 0; j < 4; j++)
            bfr[j] = *(const bf16x8*)&Bs[wn + j * 16 + l16][quad * 8];
#pragma unroll
        for (int i = 0; i < 4; i++)
#pragma unroll
            for (int j = 0; j < 4; j++)
                acc[i][j] = __builtin_amdgcn_mfma_f32_16x16x32_bf16(af[i], bfr[j], acc[i][j], 0, 0, 0);
        __syncthreads();
    }
#pragma unroll
    for (int i = 0; i < 4; i++)
#pragma unroll
        for (int j = 0; j < 4; j++)
#pragma unroll
            for (int r = 0; r < 4; r++) {
                int m = m0 + wm + i * 16 + quad * 4 + r;
                if (m < n_cnt) {
                    int n = n0 + wn + j * 16 + l16;
                    float g = gatebuf[e * T_TOK + m];
                    float v = (acc[i][j][r] + b2[e * HDIM + n]) * g;
                    eout[(size_t)(off_e + m) * HDIM + n] = (bf16)v;
                }
            }
}

// ---------------- combine: out[t] = eout[row(e0)] + eout[row(e1)] ----------------
__global__ __launch_bounds__(256) void combine_kernel(
    const bf16* __restrict__ eout, const int* __restrict__ slotbuf,
    const int* __restrict__ offs, float* __restrict__ out) {
    int t = blockIdx.x;
    int s0 = slotbuf[2 * t], s1 = slotbuf[2 * t + 1];
    int r0 = offs[s0 >> 13] + (s0 & (T_TOK - 1));
    int r1 = offs[s1 >> 13] + (s1 & (T_TOK - 1));
    const bf16* p0 = eout + (size_t)r0 * HDIM;
    const bf16* p1 = eout + (size_t)r1 * HDIM;
    float* o = out + (size_t)t * HDIM;
    int n = threadIdx.x * 4;
    bf16x4 a = *(const bf16x4*)&p0[n];
    bf16x4 b = *(const bf16x4*)&p1[n];
    float4 v = {(float)a[0] + (float)b[0], (float)a[1] + (float)b[1],
                (float)a[2] + (float)b[2], (float)a[3] + (float)b[3]};
    *(float4*)&o[n] = v;
}

extern "C" void kernel_launch(void* const* d_in, const int* in_sizes, int n_in,
                              void* d_out, int out_size, void* d_ws, size_t ws_size,
                              hipStream_t stream) {
    const float* x = (const float*)d_in[0];
    const float* rw = (const float*)d_in[1];
    const float* rb = (const float*)d_in[2];
    const float* w1 = (const float*)d_in[3];
    const float* b1 = (const float*)d_in[4];
    const float* w2 = (const float*)d_in[5];
    const float* b2 = (const float*)d_in[6];
    float* out = (float*)d_out;

    char* ws = (char*)d_ws;
    size_t o = 0;
    auto alloc = [&](size_t bytes) {
        char* p = ws + o;
        o += (bytes + 255) & ~(size_t)255;
        return p;
    };
    bf16* w1t = (bf16*)alloc((size_t)NEXP * FDIM * HDIM * 2);
    bf16* w2t = (bf16*)alloc((size_t)NEXP * HDIM * FDIM * 2);
    bf16* hbuf = (bf16*)alloc((size_t)NASSIGN * FDIM * 2);
    bf16* eout = (bf16*)alloc((size_t)NASSIGN * HDIM * 2);
    int* perm = (int*)alloc((size_t)NEXP * T_TOK * 4);
    float* gatebuf = (float*)alloc((size_t)NEXP * T_TOK * 4);
    int* slotbuf = (int*)alloc((size_t)NASSIGN * 4);
    int* cnt = (int*)alloc(256);
    int* offs = (int*)alloc(256);

    init_kernel<<<1, 64, 0, stream>>>(cnt);
    dim3 tb(32, 8);
    transpose_to_bf16<<<dim3(FDIM / 32, HDIM / 32, NEXP), tb, 0, stream>>>(w1, w1t, HDIM, FDIM);
    transpose_to_bf16<<<dim3(HDIM / 32, FDIM / 32, NEXP), tb, 0, stream>>>(w2, w2t, FDIM, HDIM);
    router_kernel<<<T_TOK / 4, 256, 0, stream>>>(x, rw, rb, cnt, perm, gatebuf, slotbuf);
    offsets_kernel<<<1, 64, 0, stream>>>(cnt, offs);
    gemm1_kernel<<<dim3(T_TOK / 128, FDIM / 128, NEXP), 256, 0, stream>>>(x, w1t, b1, cnt, offs, perm, hbuf);
    gemm2_kernel<<<dim3(T_TOK / 128, HDIM / 128, NEXP), 256, 0, stream>>>(hbuf, w2t, b2, cnt, offs, gatebuf, eout);
    combine_kernel<<<T_TOK, 256, 0, stream>>>(eout, slotbuf, offs, out);
}

// Round 2
// 689.579 us; speedup vs baseline: 1.5615x; 1.5615x over previous
//
#include <hip/hip_runtime.h>
#include <hip/hip_bf16.h>

#define T_TOK 8192
#define HDIM 1024
#define FDIM 2048
#define NEXP 8
#define ROWCAP (T_TOK * 2 + 128)  // packed rows + tail-tile slack

typedef __bf16 bf16;
typedef __bf16 bf16x4 __attribute__((ext_vector_type(4)));
typedef __bf16 bf16x8 __attribute__((ext_vector_type(8)));
typedef float f32x4 __attribute__((ext_vector_type(4)));

// async global->LDS, 16B per lane; LDS dest = wave-uniform base + lane*16
__device__ __forceinline__ void gload_lds16(const void* g, void* l) {
    __builtin_amdgcn_global_load_lds(
        (const __attribute__((address_space(1))) void*)(uintptr_t)g,
        (__attribute__((address_space(3))) void*)(uintptr_t)l,
        16, 0, 0);
}

// ---------------- init ----------------
__global__ void init_kernel(int* cnt) {
    if (threadIdx.x < NEXP) cnt[threadIdx.x] = 0;
}

// ---------------- transpose + fp32->bf16: in [E][R][C] -> out [E][C][R] ----------------
__global__ __launch_bounds__(256) void transpose_to_bf16(
    const float* __restrict__ in, bf16* __restrict__ out, int R, int C) {
    __shared__ float tile[32][33];
    int e = blockIdx.z;
    const float* inp = in + (size_t)e * R * C;
    bf16* outp = out + (size_t)e * R * C;
    int c0 = blockIdx.x * 32, r0 = blockIdx.y * 32;
    int tx = threadIdx.x, ty = threadIdx.y;  // (32,8)
#pragma unroll
    for (int i = 0; i < 4; i++)
        tile[ty + 8 * i][tx] = inp[(size_t)(r0 + ty + 8 * i) * C + c0 + tx];
    __syncthreads();
#pragma unroll
    for (int i = 0; i < 4; i++)
        outp[(size_t)(c0 + ty + 8 * i) * R + r0 + tx] = (bf16)tile[tx][ty + 8 * i];
}

// ---------------- router ----------------
__global__ __launch_bounds__(256) void router_kernel(
    const float* __restrict__ x, const float* __restrict__ rw,
    const float* __restrict__ rb, int* __restrict__ cnt, int* __restrict__ perm,
    float* __restrict__ gatebuf, int* __restrict__ slotbuf) {
    int wave = threadIdx.x >> 6;
    int lane = threadIdx.x & 63;
    int t = blockIdx.x * 4 + wave;
    float p[NEXP];
#pragma unroll
    for (int e = 0; e < NEXP; e++) p[e] = 0.f;
    const float* xt = x + (size_t)t * HDIM;
    for (int h = lane; h < HDIM; h += 64) {
        float xv = xt[h];
        const float* r = rw + h * NEXP;
#pragma unroll
        for (int e = 0; e < NEXP; e++) p[e] += xv * r[e];
    }
#pragma unroll
    for (int off = 32; off >= 1; off >>= 1) {
#pragma unroll
        for (int e = 0; e < NEXP; e++) p[e] += __shfl_xor(p[e], off, 64);
    }
    if (lane == 0) {
        float lg[NEXP];
#pragma unroll
        for (int e = 0; e < NEXP; e++) lg[e] = p[e] + rb[e];
        int e0 = 0;
#pragma unroll
        for (int e = 1; e < NEXP; e++)
            if (lg[e] > lg[e0]) e0 = e;
        int e1 = -1;
#pragma unroll
        for (int e = 0; e < NEXP; e++) {
            if (e == e0) continue;
            if (e1 < 0 || lg[e] > lg[e1]) e1 = e;
        }
        float z = expf(lg[e1] - lg[e0]);
        float g0 = 1.f / (1.f + z);
        float g1 = z / (1.f + z);
        int p0 = atomicAdd(&cnt[e0], 1);
        int p1 = atomicAdd(&cnt[e1], 1);
        perm[e0 * T_TOK + p0] = t;
        gatebuf[e0 * T_TOK + p0] = g0;
        slotbuf[2 * t] = e0 * T_TOK + p0;
        perm[e1 * T_TOK + p1] = t;
        gatebuf[e1 * T_TOK + p1] = g1;
        slotbuf[2 * t + 1] = e1 * T_TOK + p1;
    }
}

// ---------------- exclusive scan ----------------
__global__ void offsets_kernel(const int* __restrict__ cnt, int* __restrict__ offs) {
    if (threadIdx.x == 0 && blockIdx.x == 0) {
        int o = 0;
        for (int e = 0; e < NEXP; e++) {
            offs[e] = o;
            o += cnt[e];
        }
    }
}

// ---------------- pack: gather x rows per expert, fp32 -> bf16 ----------------
__global__ __launch_bounds__(256) void pack_kernel(
    const float* __restrict__ x, const int* __restrict__ perm,
    const int* __restrict__ cnt, const int* __restrict__ offs,
    bf16* __restrict__ xg) {
    int e = blockIdx.z;
    int n = cnt[e];
    int r0 = blockIdx.x * 16;
    if (r0 >= n) return;
    int wave = threadIdx.x >> 6, lane = threadIdx.x & 63;
    int base = offs[e];
#pragma unroll
    for (int i = 0; i < 4; i++) {
        int row = r0 + wave * 4 + i;
        if (row >= n) continue;  // wave-uniform branch
        int tok = perm[e * T_TOK + row];
        const float* src = x + (size_t)tok * HDIM;
        bf16* dst = xg + (size_t)(base + row) * HDIM;
#pragma unroll
        for (int it = 0; it < 4; it++) {
            int c = (it * 64 + lane) * 4;
            float4 v = *(const float4*)&src[c];
            bf16x4 b = {(bf16)v.x, (bf16)v.y, (bf16)v.z, (bf16)v.w};
            *(bf16x4*)&dst[c] = b;
        }
    }
}

// ---------------- grouped GEMM, m97-style: global_load_lds + swizzled LDS ----------------
// C[m][n] = act(A[m][:] . B[n][:] + bias[n]) (* gate[m])
// A: rows packed per expert at offs[e], ld = K. B: [E][N][K] bf16. out ld = N.
template <bool RELU, bool GATE>
__global__ __launch_bounds__(256) void moe_gemm(
    const bf16* __restrict__ A, const bf16* __restrict__ B,
    const float* __restrict__ bias, const float* __restrict__ gates,
    bf16* __restrict__ out, const int* __restrict__ cnt,
    const int* __restrict__ offs, int K, int N) {
    int e = blockIdx.z;
    int n_cnt = cnt[e];
    int m0 = blockIdx.y * 128;
    if (m0 >= n_cnt) return;
    int n0 = blockIdx.x * 128;

    __shared__ bf16 As[128 * 32];
    __shared__ bf16 Bs[128 * 32];

    int tid = threadIdx.x;
    int lane = tid & 63;
    int wave = tid >> 6;
    int wm = (wave & 1) * 64, wn = (wave >> 1) * 64;
    int quad = lane >> 4;
    int l16 = lane & 15;

    int off_e = offs[e];
    const bf16* Ae = A + (size_t)off_e * K;
    const bf16* Be = B + (size_t)e * N * K;

    // staging: lane -> tile row (lane>>2), k-chunk swizzled
    int srow = lane >> 2;
    int scol = (lane & 3) ^ ((lane >> 2) & 3) ^ ((lane >> 4) & 3);
    const bf16* ag0 = Ae + (size_t)(m0 + wave * 16 + srow) * K + scol * 8;
    const bf16* ag1 = ag0 + (size_t)64 * K;
    const bf16* bg0 = Be + (size_t)(n0 + wave * 16 + srow) * K + scol * 8;
    const bf16* bg1 = bg0 + (size_t)64 * K;
    bf16* as0 = &As[(wave * 16) * 32];
    bf16* as1 = &As[(64 + wave * 16) * 32];
    bf16* bs0 = &Bs[(wave * 16) * 32];
    bf16* bs1 = &Bs[(64 + wave * 16) * 32];

    // ds_read swizzle (consistent with staging): chunk' = quad ^ (row&3) ^ ((row>>2)&3)
    int dswz = (quad ^ (l16 & 3) ^ ((l16 >> 2) & 3)) * 8;

    f32x4 acc[4][4];
#pragma unroll
    for (int i = 0; i < 4; i++)
#pragma unroll
        for (int j = 0; j < 4; j++) acc[i][j] = f32x4{0.f, 0.f, 0.f, 0.f};

    for (int k0 = 0; k0 < K; k0 += 32) {
        gload_lds16(ag0 + k0, as0);
        gload_lds16(ag1 + k0, as1);
        gload_lds16(bg0 + k0, bs0);
        gload_lds16(bg1 + k0, bs1);
        __syncthreads();
        bf16x8 af[4], bfr[4];
#pragma unroll
        for (int i = 0; i < 4; i++)
            af[i] = *(const bf16x8*)&As[(wm + i * 16 + l16) * 32 + dswz];
#pragma unroll
        for (int j = 0; j < 4; j++)
            bfr[j] = *(const bf16x8*)&Bs[(wn + j * 16 + l16) * 32 + dswz];
#pragma unroll
        for (int i = 0; i < 4; i++)
#pragma unroll
            for (int j = 0; j < 4; j++)
                acc[i][j] = __builtin_amdgcn_mfma_f32_16x16x32_bf16(af[i], bfr[j], acc[i][j], 0, 0, 0);
        __syncthreads();
    }

#pragma unroll
    for (int i = 0; i < 4; i++)
#pragma unroll
        for (int j = 0; j < 4; j++)
#pragma unroll
            for (int r = 0; r < 4; r++) {
                int m = m0 + wm + i * 16 + quad * 4 + r;
                if (m < n_cnt) {
                    int n = n0 + wn + j * 16 + l16;
                    float v = acc[i][j][r] + bias[e * N + n];
                    if (RELU) v = v > 0.f ? v : 0.f;
                    if (GATE) v *= gates[e * T_TOK + m];
                    out[(size_t)(off_e + m) * N + n] = (bf16)v;
                }
            }
}

// ---------------- combine ----------------
__global__ __launch_bounds__(256) void combine_kernel(
    const bf16* __restrict__ eout, const int* __restrict__ slotbuf,
    const int* __restrict__ offs, float* __restrict__ out) {
    int t = blockIdx.x;
    int s0 = slotbuf[2 * t], s1 = slotbuf[2 * t + 1];
    int r0 = offs[s0 >> 13] + (s0 & (T_TOK - 1));
    int r1 = offs[s1 >> 13] + (s1 & (T_TOK - 1));
    const bf16* p0 = eout + (size_t)r0 * HDIM;
    const bf16* p1 = eout + (size_t)r1 * HDIM;
    float* o = out + (size_t)t * HDIM;
    int n = threadIdx.x * 4;
    bf16x4 a = *(const bf16x4*)&p0[n];
    bf16x4 b = *(const bf16x4*)&p1[n];
    float4 v = {(float)a[0] + (float)b[0], (float)a[1] + (float)b[1],
                (float)a[2] + (float)b[2], (float)a[3] + (float)b[3]};
    *(float4*)&o[n] = v;
}

extern "C" void kernel_launch(void* const* d_in, const int* in_sizes, int n_in,
                              void* d_out, int out_size, void* d_ws, size_t ws_size,
                              hipStream_t stream) {
    const float* x = (const float*)d_in[0];
    const float* rw = (const float*)d_in[1];
    const float* rb = (const float*)d_in[2];
    const float* w1 = (const float*)d_in[3];
    const float* b1 = (const float*)d_in[4];
    const float* w2 = (const float*)d_in[5];
    const float* b2 = (const float*)d_in[6];
    float* out = (float*)d_out;

    char* ws = (char*)d_ws;
    size_t o = 0;
    auto alloc = [&](size_t bytes) {
        char* p = ws + o;
        o += (bytes + 255) & ~(size_t)255;
        return p;
    };
    bf16* w1t = (bf16*)alloc((size_t)NEXP * FDIM * HDIM * 2);
    bf16* w2t = (bf16*)alloc((size_t)NEXP * HDIM * FDIM * 2);
    bf16* hbuf = (bf16*)alloc((size_t)ROWCAP * FDIM * 2);
    bf16* xg = (bf16*)alloc((size_t)ROWCAP * HDIM * 2);  // aliased: xg (gemm1 A) then eout (gemm2 out)
    bf16* eout = xg;
    int* perm = (int*)alloc((size_t)NEXP * T_TOK * 4);
    float* gatebuf = (float*)alloc((size_t)NEXP * T_TOK * 4);
    int* slotbuf = (int*)alloc((size_t)NEXP * T_TOK * 4);
    int* cnt = (int*)alloc(256);
    int* offs = (int*)alloc(256);

    init_kernel<<<1, 64, 0, stream>>>(cnt);
    dim3 tb(32, 8);
    transpose_to_bf16<<<dim3(FDIM / 32, HDIM / 32, NEXP), tb, 0, stream>>>(w1, w1t, HDIM, FDIM);
    transpose_to_bf16<<<dim3(HDIM / 32, FDIM / 32, NEXP), tb, 0, stream>>>(w2, w2t, FDIM, HDIM);
    router_kernel<<<T_TOK / 4, 256, 0, stream>>>(x, rw, rb, cnt, perm, gatebuf, slotbuf);
    offsets_kernel<<<1, 64, 0, stream>>>(cnt, offs);
    pack_kernel<<<dim3(T_TOK / 16, 1, NEXP), 256, 0, stream>>>(x, perm, cnt, offs, xg);
    // gemm1: h = relu(xg @ w1t^T + b1) -> hbuf [rows][FDIM]
    moe_gemm<true, false><<<dim3(FDIM / 128, T_TOK / 128, NEXP), 256, 0, stream>>>(
        xg, w1t, b1, nullptr, hbuf, cnt, offs, HDIM, FDIM);
    // gemm2: eout = gate * (hbuf @ w2t^T + b2) -> eout [rows][HDIM]
    moe_gemm<false, true><<<dim3(HDIM / 128, T_TOK / 128, NEXP), 256, 0, stream>>>(
        hbuf, w2t, b2, gatebuf, eout, cnt, offs, FDIM, HDIM);
    combine_kernel<<<T_TOK, 256, 0, stream>>>(eout, slotbuf, offs, out);
}

// Round 3
// 676.608 us; speedup vs baseline: 1.5914x; 1.0192x over previous
//
#include <hip/hip_runtime.h>
#include <hip/hip_bf16.h>

#define T_TOK 8192
#define HDIM 1024
#define FDIM 2048
#define NEXP 8
#define ROWCAP (T_TOK * 2 + 128)  // packed rows + tail-tile slack

typedef __bf16 bf16;
typedef __bf16 bf16x4 __attribute__((ext_vector_type(4)));
typedef __bf16 bf16x8 __attribute__((ext_vector_type(8)));
typedef float f32x4 __attribute__((ext_vector_type(4)));

// async global->LDS, 16B per lane; LDS dest = wave-uniform base + lane*16
__device__ __forceinline__ void gload_lds16(const void* g, void* l) {
    __builtin_amdgcn_global_load_lds(
        (const __attribute__((address_space(1))) void*)(uintptr_t)g,
        (__attribute__((address_space(3))) void*)(uintptr_t)l,
        16, 0, 0);
}

// ---------------- init ----------------
__global__ void init_kernel(int* cnt) {
    if (threadIdx.x < NEXP) cnt[threadIdx.x] = 0;
}

// ---------------- transpose + fp32->bf16: in [E][R][C] fp32 -> out [E][C][R] bf16 ----------------
// 64x64 tiles, float4 loads, bf16x8 (16B) coalesced stores.
__global__ __launch_bounds__(256) void transpose_to_bf16(
    const float* __restrict__ in, bf16* __restrict__ out, int R, int C) {
    __shared__ float tile[64][68];  // stride 68 dwords: float4 LDS ops stay 16B-aligned
    int e = blockIdx.z;
    const float* inp = in + (size_t)e * R * C;
    bf16* outp = out + (size_t)e * R * C;
    int c0 = blockIdx.x * 64, r0 = blockIdx.y * 64;
    int tid = threadIdx.x;
    int tx = tid & 15, ty = tid >> 4;
#pragma unroll
    for (int i = 0; i < 4; i++) {
        int row = ty + i * 16;
        float4 v = *(const float4*)&inp[(size_t)(r0 + row) * C + c0 + tx * 4];
        *(float4*)&tile[row][tx * 4] = v;
    }
    __syncthreads();
#pragma unroll
    for (int i = 0; i < 2; i++) {
        int idx = tid + i * 256;
        int c = idx >> 3, seg = idx & 7;
        bf16x8 v;
#pragma unroll
        for (int j = 0; j < 8; j++) v[j] = (bf16)tile[seg * 8 + j][c];
        *(bf16x8*)&outp[(size_t)(c0 + c) * R + r0 + seg * 8] = v;
    }
}

// ---------------- router: rw staged in LDS, float4 x loads, 8 tokens/wave ----------------
__global__ __launch_bounds__(256) void router_kernel(
    const float* __restrict__ x, const float* __restrict__ rw,
    const float* __restrict__ rb, int* __restrict__ cnt, int* __restrict__ perm,
    float* __restrict__ gatebuf, int* __restrict__ slotbuf) {
    __shared__ float rwT[NEXP][HDIM];
    __shared__ float rbs[NEXP];
    int tid = threadIdx.x;
    // stage rw transposed: rw[h][e] -> rwT[e][h]
    for (int i = tid; i < HDIM * NEXP / 4; i += 256) {
        float4 v = ((const float4*)rw)[i];
        int h = i >> 1, e0 = (i & 1) * 4;
        rwT[e0 + 0][h] = v.x;
        rwT[e0 + 1][h] = v.y;
        rwT[e0 + 2][h] = v.z;
        rwT[e0 + 3][h] = v.w;
    }
    if (tid < NEXP) rbs[tid] = rb[tid];
    __syncthreads();
    int wave = tid >> 6, lane = tid & 63;
    int tbase = blockIdx.x * 32 + wave * 8;

    float4 xv[4];
    {
        const float4* xt = (const float4*)(x + (size_t)tbase * HDIM);
#pragma unroll
        for (int it = 0; it < 4; it++) xv[it] = xt[it * 64 + lane];
    }
    for (int tk = 0; tk < 8; tk++) {
        int t = tbase + tk;
        float4 nxt[4];
        if (tk < 7) {
            const float4* xt = (const float4*)(x + (size_t)(t + 1) * HDIM);
#pragma unroll
            for (int it = 0; it < 4; it++) nxt[it] = xt[it * 64 + lane];
        }
        float p[NEXP];
#pragma unroll
        for (int e = 0; e < NEXP; e++) p[e] = 0.f;
#pragma unroll
        for (int it = 0; it < 4; it++) {
            int h = (it * 64 + lane) * 4;
            float4 v = xv[it];
#pragma unroll
            for (int e = 0; e < NEXP; e++) {
                float4 wv = *(const float4*)&rwT[e][h];
                p[e] += v.x * wv.x + v.y * wv.y + v.z * wv.z + v.w * wv.w;
            }
        }
#pragma unroll
        for (int off = 32; off >= 1; off >>= 1) {
#pragma unroll
            for (int e = 0; e < NEXP; e++) p[e] += __shfl_xor(p[e], off, 64);
        }
        if (lane == 0) {
            float lg[NEXP];
#pragma unroll
            for (int e = 0; e < NEXP; e++) lg[e] = p[e] + rbs[e];
            int e0 = 0;
#pragma unroll
            for (int e = 1; e < NEXP; e++)
                if (lg[e] > lg[e0]) e0 = e;
            int e1 = -1;
#pragma unroll
            for (int e = 0; e < NEXP; e++) {
                if (e == e0) continue;
                if (e1 < 0 || lg[e] > lg[e1]) e1 = e;
            }
            float z = expf(lg[e1] - lg[e0]);
            float g0 = 1.f / (1.f + z);
            float g1 = z / (1.f + z);
            int p0 = atomicAdd(&cnt[e0], 1);
            int p1 = atomicAdd(&cnt[e1], 1);
            perm[e0 * T_TOK + p0] = t;
            gatebuf[e0 * T_TOK + p0] = g0;
            slotbuf[2 * t] = e0 * T_TOK + p0;
            perm[e1 * T_TOK + p1] = t;
            gatebuf[e1 * T_TOK + p1] = g1;
            slotbuf[2 * t + 1] = e1 * T_TOK + p1;
        }
#pragma unroll
        for (int it = 0; it < 4; it++) xv[it] = nxt[it];
    }
}

// ---------------- exclusive scan ----------------
__global__ void offsets_kernel(const int* __restrict__ cnt, int* __restrict__ offs) {
    if (threadIdx.x == 0 && blockIdx.x == 0) {
        int o = 0;
        for (int e = 0; e < NEXP; e++) {
            offs[e] = o;
            o += cnt[e];
        }
    }
}

// ---------------- pack: gather x rows per expert, fp32 -> bf16 ----------------
__global__ __launch_bounds__(256) void pack_kernel(
    const float* __restrict__ x, const int* __restrict__ perm,
    const int* __restrict__ cnt, const int* __restrict__ offs,
    bf16* __restrict__ xg) {
    int e = blockIdx.z;
    int n = cnt[e];
    int r0 = blockIdx.x * 16;
    if (r0 >= n) return;
    int wave = threadIdx.x >> 6, lane = threadIdx.x & 63;
    int base = offs[e];
#pragma unroll
    for (int i = 0; i < 4; i++) {
        int row = r0 + wave * 4 + i;
        if (row >= n) continue;  // wave-uniform branch
        int tok = perm[e * T_TOK + row];
        const float* src = x + (size_t)tok * HDIM;
        bf16* dst = xg + (size_t)(base + row) * HDIM;
#pragma unroll
        for (int it = 0; it < 4; it++) {
            int c = (it * 64 + lane) * 4;
            float4 v = *(const float4*)&src[c];
            bf16x4 b = {(bf16)v.x, (bf16)v.y, (bf16)v.z, (bf16)v.w};
            *(bf16x4*)&dst[c] = b;
        }
    }
}

// ---------------- grouped GEMM, m97-style: global_load_lds + swizzled LDS ----------------
template <bool RELU, bool GATE>
__global__ __launch_bounds__(256) void moe_gemm(
    const bf16* __restrict__ A, const bf16* __restrict__ B,
    const float* __restrict__ bias, const float* __restrict__ gates,
    bf16* __restrict__ out, const int* __restrict__ cnt,
    const int* __restrict__ offs, int K, int N) {
    int e = blockIdx.z;
    int n_cnt = cnt[e];
    int m0 = blockIdx.y * 128;
    if (m0 >= n_cnt) return;
    int n0 = blockIdx.x * 128;

    __shared__ bf16 As[128 * 32];
    __shared__ bf16 Bs[128 * 32];

    int tid = threadIdx.x;
    int lane = tid & 63;
    int wave = tid >> 6;
    int wm = (wave & 1) * 64, wn = (wave >> 1) * 64;
    int quad = lane >> 4;
    int l16 = lane & 15;

    int off_e = offs[e];
    const bf16* Ae = A + (size_t)off_e * K;
    const bf16* Be = B + (size_t)e * N * K;

    int srow = lane >> 2;
    int scol = (lane & 3) ^ ((lane >> 2) & 3) ^ ((lane >> 4) & 3);
    const bf16* ag0 = Ae + (size_t)(m0 + wave * 16 + srow) * K + scol * 8;
    const bf16* ag1 = ag0 + (size_t)64 * K;
    const bf16* bg0 = Be + (size_t)(n0 + wave * 16 + srow) * K + scol * 8;
    const bf16* bg1 = bg0 + (size_t)64 * K;
    bf16* as0 = &As[(wave * 16) * 32];
    bf16* as1 = &As[(64 + wave * 16) * 32];
    bf16* bs0 = &Bs[(wave * 16) * 32];
    bf16* bs1 = &Bs[(64 + wave * 16) * 32];

    int dswz = (quad ^ (l16 & 3) ^ ((l16 >> 2) & 3)) * 8;

    f32x4 acc[4][4];
#pragma unroll
    for (int i = 0; i < 4; i++)
#pragma unroll
        for (int j = 0; j < 4; j++) acc[i][j] = f32x4{0.f, 0.f, 0.f, 0.f};

    for (int k0 = 0; k0 < K; k0 += 32) {
        gload_lds16(ag0 + k0, as0);
        gload_lds16(ag1 + k0, as1);
        gload_lds16(bg0 + k0, bs0);
        gload_lds16(bg1 + k0, bs1);
        __syncthreads();
        bf16x8 af[4], bfr[4];
#pragma unroll
        for (int i = 0; i < 4; i++)
            af[i] = *(const bf16x8*)&As[(wm + i * 16 + l16) * 32 + dswz];
#pragma unroll
        for (int j = 0; j < 4; j++)
            bfr[j] = *(const bf16x8*)&Bs[(wn + j * 16 + l16) * 32 + dswz];
#pragma unroll
        for (int i = 0; i < 4; i++)
#pragma unroll
            for (int j = 0; j < 4; j++)
                acc[i][j] = __builtin_amdgcn_mfma_f32_16x16x32_bf16(af[i], bfr[j], acc[i][j], 0, 0, 0);
        __syncthreads();
    }

#pragma unroll
    for (int i = 0; i < 4; i++)
#pragma unroll
        for (int j = 0; j < 4; j++)
#pragma unroll
            for (int r = 0; r < 4; r++) {
                int m = m0 + wm + i * 16 + quad * 4 + r;
                if (m < n_cnt) {
                    int n = n0 + wn + j * 16 + l16;
                    float v = acc[i][j][r] + bias[e * N + n];
                    if (RELU) v = v > 0.f ? v : 0.f;
                    if (GATE) v *= gates[e * T_TOK + m];
                    out[(size_t)(off_e + m) * N + n] = (bf16)v;
                }
            }
}

// ---------------- combine ----------------
__global__ __launch_bounds__(256) void combine_kernel(
    const bf16* __restrict__ eout, const int* __restrict__ slotbuf,
    const int* __restrict__ offs, float* __restrict__ out) {
    int t = blockIdx.x;
    int s0 = slotbuf[2 * t], s1 = slotbuf[2 * t + 1];
    int r0 = offs[s0 >> 13] + (s0 & (T_TOK - 1));
    int r1 = offs[s1 >> 13] + (s1 & (T_TOK - 1));
    const bf16* p0 = eout + (size_t)r0 * HDIM;
    const bf16* p1 = eout + (size_t)r1 * HDIM;
    float* o = out + (size_t)t * HDIM;
    int n = threadIdx.x * 4;
    bf16x4 a = *(const bf16x4*)&p0[n];
    bf16x4 b = *(const bf16x4*)&p1[n];
    float4 v = {(float)a[0] + (float)b[0], (float)a[1] + (float)b[1],
                (float)a[2] + (float)b[2], (float)a[3] + (float)b[3]};
    *(float4*)&o[n] = v;
}

extern "C" void kernel_launch(void* const* d_in, const int* in_sizes, int n_in,
                              void* d_out, int out_size, void* d_ws, size_t ws_size,
                              hipStream_t stream) {
    const float* x = (const float*)d_in[0];
    const float* rw = (const float*)d_in[1];
    const float* rb = (const float*)d_in[2];
    const float* w1 = (const float*)d_in[3];
    const float* b1 = (const float*)d_in[4];
    const float* w2 = (const float*)d_in[5];
    const float* b2 = (const float*)d_in[6];
    float* out = (float*)d_out;

    char* ws = (char*)d_ws;
    size_t o = 0;
    auto alloc = [&](size_t bytes) {
        char* p = ws + o;
        o += (bytes + 255) & ~(size_t)255;
        return p;
    };
    bf16* w1t = (bf16*)alloc((size_t)NEXP * FDIM * HDIM * 2);
    bf16* w2t = (bf16*)alloc((size_t)NEXP * HDIM * FDIM * 2);
    bf16* hbuf = (bf16*)alloc((size_t)ROWCAP * FDIM * 2);
    bf16* xg = (bf16*)alloc((size_t)ROWCAP * HDIM * 2);  // aliased: xg (gemm1 A) then eout (gemm2 out)
    bf16* eout = xg;
    int* perm = (int*)alloc((size_t)NEXP * T_TOK * 4);
    float* gatebuf = (float*)alloc((size_t)NEXP * T_TOK * 4);
    int* slotbuf = (int*)alloc((size_t)NEXP * T_TOK * 4);
    int* cnt = (int*)alloc(256);
    int* offs = (int*)alloc(256);

    init_kernel<<<1, 64, 0, stream>>>(cnt);
    transpose_to_bf16<<<dim3(FDIM / 64, HDIM / 64, NEXP), 256, 0, stream>>>(w1, w1t, HDIM, FDIM);
    transpose_to_bf16<<<dim3(HDIM / 64, FDIM / 64, NEXP), 256, 0, stream>>>(w2, w2t, FDIM, HDIM);
    router_kernel<<<T_TOK / 32, 256, 0, stream>>>(x, rw, rb, cnt, perm, gatebuf, slotbuf);
    offsets_kernel<<<1, 64, 0, stream>>>(cnt, offs);
    pack_kernel<<<dim3(T_TOK / 16, 1, NEXP), 256, 0, stream>>>(x, perm, cnt, offs, xg);
    moe_gemm<true, false><<<dim3(FDIM / 128, T_TOK / 128, NEXP), 256, 0, stream>>>(
        xg, w1t, b1, nullptr, hbuf, cnt, offs, HDIM, FDIM);
    moe_gemm<false, true><<<dim3(HDIM / 128, T_TOK / 128, NEXP), 256, 0, stream>>>(
        hbuf, w2t, b2, gatebuf, eout, cnt, offs, FDIM, HDIM);
    combine_kernel<<<T_TOK, 256, 0, stream>>>(eout, slotbuf, offs, out);
}

// Round 4
// 512.342 us; speedup vs baseline: 2.1017x; 1.3206x over previous
//
#include <hip/hip_runtime.h>
#include <hip/hip_bf16.h>

#define T_TOK 8192
#define HDIM 1024
#define FDIM 2048
#define NEXP 8
#define NASSIGN (T_TOK * 2)
#define ROWCAP (NASSIGN + 128)  // packed rows + tail-tile slack
#define NHB 64                  // hist/scatter blocks

typedef __bf16 bf16;
typedef __bf16 bf16x4 __attribute__((ext_vector_type(4)));
typedef __bf16 bf16x8 __attribute__((ext_vector_type(8)));
typedef float f32x4 __attribute__((ext_vector_type(4)));

// async global->LDS, 16B per lane; LDS dest = wave-uniform base + lane*16
__device__ __forceinline__ void gload_lds16(const void* g, void* l) {
    __builtin_amdgcn_global_load_lds(
        (const __attribute__((address_space(1))) void*)(uintptr_t)g,
        (__attribute__((address_space(3))) void*)(uintptr_t)l,
        16, 0, 0);
}

// ---------------- transpose + fp32->bf16: in [E][R][C] fp32 -> out [E][C][R] bf16 ----------------
__global__ __launch_bounds__(256) void transpose_to_bf16(
    const float* __restrict__ in, bf16* __restrict__ out, int R, int C) {
    __shared__ float tile[64][68];
    int e = blockIdx.z;
    const float* inp = in + (size_t)e * R * C;
    bf16* outp = out + (size_t)e * R * C;
    int c0 = blockIdx.x * 64, r0 = blockIdx.y * 64;
    int tid = threadIdx.x;
    int tx = tid & 15, ty = tid >> 4;
#pragma unroll
    for (int i = 0; i < 4; i++) {
        int row = ty + i * 16;
        float4 v = *(const float4*)&inp[(size_t)(r0 + row) * C + c0 + tx * 4];
        *(float4*)&tile[row][tx * 4] = v;
    }
    __syncthreads();
#pragma unroll
    for (int i = 0; i < 2; i++) {
        int idx = tid + i * 256;
        int c = idx >> 3, seg = idx & 7;
        bf16x8 v;
#pragma unroll
        for (int j = 0; j < 8; j++) v[j] = (bf16)tile[seg * 8 + j][c];
        *(bf16x8*)&outp[(size_t)(c0 + c) * R + r0 + seg * 8] = v;
    }
}

// ---------------- phase A: per-token top-2 + gates (NO atomics) ----------------
__global__ __launch_bounds__(256) void router_kernel(
    const float* __restrict__ x, const float* __restrict__ rw,
    const float* __restrict__ rb, int* __restrict__ expert_pair,
    float2* __restrict__ gate_pair) {
    __shared__ float rwT[NEXP][HDIM];
    __shared__ float rbs[NEXP];
    int tid = threadIdx.x;
    for (int i = tid; i < HDIM * NEXP / 4; i += 256) {
        float4 v = ((const float4*)rw)[i];
        int h = i >> 1, e0 = (i & 1) * 4;
        rwT[e0 + 0][h] = v.x;
        rwT[e0 + 1][h] = v.y;
        rwT[e0 + 2][h] = v.z;
        rwT[e0 + 3][h] = v.w;
    }
    if (tid < NEXP) rbs[tid] = rb[tid];
    __syncthreads();
    int wave = tid >> 6, lane = tid & 63;
    int tbase = blockIdx.x * 32 + wave * 8;

    for (int tk = 0; tk < 8; tk++) {
        int t = tbase + tk;
        const float4* xt = (const float4*)(x + (size_t)t * HDIM);
        float p[NEXP];
#pragma unroll
        for (int e = 0; e < NEXP; e++) p[e] = 0.f;
#pragma unroll
        for (int it = 0; it < 4; it++) {
            float4 v = xt[it * 64 + lane];
            int h = (it * 64 + lane) * 4;
#pragma unroll
            for (int e = 0; e < NEXP; e++) {
                float4 wv = *(const float4*)&rwT[e][h];
                p[e] += v.x * wv.x + v.y * wv.y + v.z * wv.z + v.w * wv.w;
            }
        }
#pragma unroll
        for (int off = 32; off >= 1; off >>= 1) {
#pragma unroll
            for (int e = 0; e < NEXP; e++) p[e] += __shfl_xor(p[e], off, 64);
        }
        if (lane == 0) {
            float lg[NEXP];
#pragma unroll
            for (int e = 0; e < NEXP; e++) lg[e] = p[e] + rbs[e];
            int e0 = 0;
#pragma unroll
            for (int e = 1; e < NEXP; e++)
                if (lg[e] > lg[e0]) e0 = e;
            int e1 = -1;
#pragma unroll
            for (int e = 0; e < NEXP; e++) {
                if (e == e0) continue;
                if (e1 < 0 || lg[e] > lg[e1]) e1 = e;
            }
            float z = expf(lg[e1] - lg[e0]);
            expert_pair[t] = e0 | (e1 << 16);
            gate_pair[t] = make_float2(1.f / (1.f + z), z / (1.f + z));
        }
    }
}

// ---------------- phase B: per-block expert histogram via ballots ----------------
__global__ __launch_bounds__(256) void hist_kernel(
    const int* __restrict__ expert_pair, int* __restrict__ hist) {
    int tid = threadIdx.x;
    int wave = tid >> 6, lane = tid & 63;
    int a = blockIdx.x * 256 + tid;
    int t = a >> 1, j = a & 1;
    int e = (expert_pair[t] >> (16 * j)) & 0xffff;
    __shared__ int wcnt[4][NEXP];
#pragma unroll
    for (int ee = 0; ee < NEXP; ee++) {
        unsigned long long m = __ballot(e == ee);
        if (lane == 0) wcnt[wave][ee] = __popcll(m);
    }
    __syncthreads();
    if (tid < NEXP)
        hist[blockIdx.x * NEXP + tid] =
            wcnt[0][tid] + wcnt[1][tid] + wcnt[2][tid] + wcnt[3][tid];
}

// ---------------- phase C: scan -> cnt, offs, per-block starts ----------------
__global__ __launch_bounds__(256) void scan_kernel(
    const int* __restrict__ hist, int* __restrict__ start,
    int* __restrict__ cnt, int* __restrict__ offs) {
    __shared__ int h[NHB * NEXP];
    __shared__ int tot[NEXP];
    __shared__ int offsh[NEXP];
    int tid = threadIdx.x;
    for (int i = tid; i < NHB * NEXP; i += 256) h[i] = hist[i];
    __syncthreads();
    if (tid < NEXP) {
        int s = 0;
        for (int b = 0; b < NHB; b++) s += h[b * NEXP + tid];
        tot[tid] = s;
        cnt[tid] = s;
    }
    __syncthreads();
    if (tid == 0) {
        int o = 0;
        for (int e = 0; e < NEXP; e++) {
            offsh[e] = o;
            offs[e] = o;
            o += tot[e];
        }
    }
    __syncthreads();
    if (tid < NEXP) {
        int run = offsh[tid];
        for (int b = 0; b < NHB; b++) {
            start[b * NEXP + tid] = run;
            run += h[b * NEXP + tid];
        }
    }
}

// ---------------- phase D: deterministic scatter via ballot ranks ----------------
__global__ __launch_bounds__(256) void scatter_kernel(
    const int* __restrict__ expert_pair, const float2* __restrict__ gate_pair,
    const int* __restrict__ start, int* __restrict__ perm,
    float* __restrict__ gatebuf, int* __restrict__ rowbuf) {
    int tid = threadIdx.x;
    int wave = tid >> 6, lane = tid & 63;
    int a = blockIdx.x * 256 + tid;
    int t = a >> 1, j = a & 1;
    int e = (expert_pair[t] >> (16 * j)) & 0xffff;
    float2 gp = gate_pair[t];
    float g = j ? gp.y : gp.x;
    __shared__ int wcnt[4][NEXP];
    int rankw = 0;
    unsigned long long below = (1ull << lane) - 1ull;
#pragma unroll
    for (int ee = 0; ee < NEXP; ee++) {
        unsigned long long m = __ballot(e == ee);
        if (lane == 0) wcnt[wave][ee] = __popcll(m);
        if (ee == e) rankw = __popcll(m & below);
    }
    __syncthreads();
    int cross = 0;
    for (int w = 0; w < wave; w++) cross += wcnt[w][e];
    int pos = start[blockIdx.x * NEXP + e] + cross + rankw;
    perm[pos] = t;
    gatebuf[pos] = g;
    rowbuf[a] = pos;
}

// ---------------- pack: gather x rows into packed order, fp32 -> bf16 ----------------
__global__ __launch_bounds__(256) void pack_kernel(
    const float* __restrict__ x, const int* __restrict__ perm,
    bf16* __restrict__ xg) {
    int r0 = blockIdx.x * 16;
    int wave = threadIdx.x >> 6, lane = threadIdx.x & 63;
#pragma unroll
    for (int i = 0; i < 4; i++) {
        int row = r0 + wave * 4 + i;
        int tok = perm[row];
        const float* src = x + (size_t)tok * HDIM;
        bf16* dst = xg + (size_t)row * HDIM;
#pragma unroll
        for (int it = 0; it < 4; it++) {
            int c = (it * 64 + lane) * 4;
            float4 v = *(const float4*)&src[c];
            bf16x4 b = {(bf16)v.x, (bf16)v.y, (bf16)v.z, (bf16)v.w};
            *(bf16x4*)&dst[c] = b;
        }
    }
}

// ---------------- grouped GEMM, m97-style: global_load_lds + swizzled LDS ----------------
template <bool RELU, bool GATE>
__global__ __launch_bounds__(256) void moe_gemm(
    const bf16* __restrict__ A, const bf16* __restrict__ B,
    const float* __restrict__ bias, const float* __restrict__ gates,
    bf16* __restrict__ out, const int* __restrict__ cnt,
    const int* __restrict__ offs, int K, int N) {
    int e = blockIdx.z;
    int n_cnt = cnt[e];
    int m0 = blockIdx.y * 128;
    if (m0 >= n_cnt) return;
    int n0 = blockIdx.x * 128;

    __shared__ bf16 As[128 * 32];
    __shared__ bf16 Bs[128 * 32];

    int tid = threadIdx.x;
    int lane = tid & 63;
    int wave = tid >> 6;
    int wm = (wave & 1) * 64, wn = (wave >> 1) * 64;
    int quad = lane >> 4;
    int l16 = lane & 15;

    int off_e = offs[e];
    const bf16* Ae = A + (size_t)off_e * K;
    const bf16* Be = B + (size_t)e * N * K;

    int srow = lane >> 2;
    int scol = (lane & 3) ^ ((lane >> 2) & 3) ^ ((lane >> 4) & 3);
    const bf16* ag0 = Ae + (size_t)(m0 + wave * 16 + srow) * K + scol * 8;
    const bf16* ag1 = ag0 + (size_t)64 * K;
    const bf16* bg0 = Be + (size_t)(n0 + wave * 16 + srow) * K + scol * 8;
    const bf16* bg1 = bg0 + (size_t)64 * K;
    bf16* as0 = &As[(wave * 16) * 32];
    bf16* as1 = &As[(64 + wave * 16) * 32];
    bf16* bs0 = &Bs[(wave * 16) * 32];
    bf16* bs1 = &Bs[(64 + wave * 16) * 32];

    int dswz = (quad ^ (l16 & 3) ^ ((l16 >> 2) & 3)) * 8;

    f32x4 acc[4][4];
#pragma unroll
    for (int i = 0; i < 4; i++)
#pragma unroll
        for (int j = 0; j < 4; j++) acc[i][j] = f32x4{0.f, 0.f, 0.f, 0.f};

    for (int k0 = 0; k0 < K; k0 += 32) {
        gload_lds16(ag0 + k0, as0);
        gload_lds16(ag1 + k0, as1);
        gload_lds16(bg0 + k0, bs0);
        gload_lds16(bg1 + k0, bs1);
        __syncthreads();
        bf16x8 af[4], bfr[4];
#pragma unroll
        for (int i = 0; i < 4; i++)
            af[i] = *(const bf16x8*)&As[(wm + i * 16 + l16) * 32 + dswz];
#pragma unroll
        for (int j = 0; j < 4; j++)
            bfr[j] = *(const bf16x8*)&Bs[(wn + j * 16 + l16) * 32 + dswz];
#pragma unroll
        for (int i = 0; i < 4; i++)
#pragma unroll
            for (int j = 0; j < 4; j++)
                acc[i][j] = __builtin_amdgcn_mfma_f32_16x16x32_bf16(af[i], bfr[j], acc[i][j], 0, 0, 0);
        __syncthreads();
    }

#pragma unroll
    for (int i = 0; i < 4; i++)
#pragma unroll
        for (int j = 0; j < 4; j++)
#pragma unroll
            for (int r = 0; r < 4; r++) {
                int m = m0 + wm + i * 16 + quad * 4 + r;
                if (m < n_cnt) {
                    int n = n0 + wn + j * 16 + l16;
                    float v = acc[i][j][r] + bias[e * N + n];
                    if (RELU) v = v > 0.f ? v : 0.f;
                    if (GATE) v *= gates[off_e + m];
                    out[(size_t)(off_e + m) * N + n] = (bf16)v;
                }
            }
}

// ---------------- combine ----------------
__global__ __launch_bounds__(256) void combine_kernel(
    const bf16* __restrict__ eout, const int* __restrict__ rowbuf,
    float* __restrict__ out) {
    int t = blockIdx.x;
    int r0 = rowbuf[2 * t], r1 = rowbuf[2 * t + 1];
    const bf16* p0 = eout + (size_t)r0 * HDIM;
    const bf16* p1 = eout + (size_t)r1 * HDIM;
    float* o = out + (size_t)t * HDIM;
    int n = threadIdx.x * 4;
    bf16x4 a = *(const bf16x4*)&p0[n];
    bf16x4 b = *(const bf16x4*)&p1[n];
    float4 v = {(float)a[0] + (float)b[0], (float)a[1] + (float)b[1],
                (float)a[2] + (float)b[2], (float)a[3] + (float)b[3]};
    *(float4*)&o[n] = v;
}

extern "C" void kernel_launch(void* const* d_in, const int* in_sizes, int n_in,
                              void* d_out, int out_size, void* d_ws, size_t ws_size,
                              hipStream_t stream) {
    const float* x = (const float*)d_in[0];
    const float* rw = (const float*)d_in[1];
    const float* rb = (const float*)d_in[2];
    const float* w1 = (const float*)d_in[3];
    const float* b1 = (const float*)d_in[4];
    const float* w2 = (const float*)d_in[5];
    const float* b2 = (const float*)d_in[6];
    float* out = (float*)d_out;

    char* ws = (char*)d_ws;
    size_t o = 0;
    auto alloc = [&](size_t bytes) {
        char* p = ws + o;
        o += (bytes + 255) & ~(size_t)255;
        return p;
    };
    bf16* w1t = (bf16*)alloc((size_t)NEXP * FDIM * HDIM * 2);
    bf16* w2t = (bf16*)alloc((size_t)NEXP * HDIM * FDIM * 2);
    bf16* hbuf = (bf16*)alloc((size_t)ROWCAP * FDIM * 2);
    bf16* xg = (bf16*)alloc((size_t)ROWCAP * HDIM * 2);  // aliased: xg (gemm1 A) then eout (gemm2 out)
    bf16* eout = xg;
    int* expert_pair = (int*)alloc((size_t)T_TOK * 4);
    float2* gate_pair = (float2*)alloc((size_t)T_TOK * 8);
    int* hist = (int*)alloc((size_t)NHB * NEXP * 4);
    int* start = (int*)alloc((size_t)NHB * NEXP * 4);
    int* perm = (int*)alloc((size_t)NASSIGN * 4);
    float* gatebuf = (float*)alloc((size_t)NASSIGN * 4);
    int* rowbuf = (int*)alloc((size_t)NASSIGN * 4);
    int* cnt = (int*)alloc(256);
    int* offs = (int*)alloc(256);

    transpose_to_bf16<<<dim3(FDIM / 64, HDIM / 64, NEXP), 256, 0, stream>>>(w1, w1t, HDIM, FDIM);
    transpose_to_bf16<<<dim3(HDIM / 64, FDIM / 64, NEXP), 256, 0, stream>>>(w2, w2t, FDIM, HDIM);
    router_kernel<<<T_TOK / 32, 256, 0, stream>>>(x, rw, rb, expert_pair, gate_pair);
    hist_kernel<<<NHB, 256, 0, stream>>>(expert_pair, hist);
    scan_kernel<<<1, 256, 0, stream>>>(hist, start, cnt, offs);
    scatter_kernel<<<NHB, 256, 0, stream>>>(expert_pair, gate_pair, start, perm, gatebuf, rowbuf);
    pack_kernel<<<NASSIGN / 16, 256, 0, stream>>>(x, perm, xg);
    moe_gemm<true, false><<<dim3(FDIM / 128, T_TOK / 128, NEXP), 256, 0, stream>>>(
        xg, w1t, b1, nullptr, hbuf, cnt, offs, HDIM, FDIM);
    moe_gemm<false, true><<<dim3(HDIM / 128, T_TOK / 128, NEXP), 256, 0, stream>>>(
        hbuf, w2t, b2, gatebuf, eout, cnt, offs, FDIM, HDIM);
    combine_kernel<<<T_TOK, 256, 0, stream>>>(eout, rowbuf, out);
}